// Round 1
// baseline (164.658 us; speedup 1.0000x reference)
//
#include <hip/hip_runtime.h>

// Problem constants (B=4, S=4096, H=16, Dk=Dv=64)
constexpr int HH   = 16;
constexpr int DK   = 64;
constexpr int DV   = 64;
constexpr int ROWS = 16384;           // B*S
constexpr int TS   = 32;              // tile rows staged per iteration
constexpr int NCHUNK = 64;            // s-chunks (grid.x)
constexpr int RPC  = ROWS / NCHUNK;   // 256 rows per block
constexpr int NT   = RPC / TS;        // 8 tiles per block
constexpr float DECAY = 0.95f;

__global__ __launch_bounds__(256) void init_out(const float* __restrict__ mem,
                                                float* __restrict__ out) {
    int i = blockIdx.x * blockDim.x + threadIdx.x;
    out[i] = DECAY * mem[i];
}

__global__ __launch_bounds__(256) void accum(const float* __restrict__ keys,
                                             const float* __restrict__ values,
                                             const float* __restrict__ rho,
                                             float* __restrict__ out) {
    // Double-buffered tiles: 2 * (32*64 + 32*64) * 4B = 32 KiB
    __shared__ float sK[2][TS * DK];
    __shared__ float sV[2][TS * DV];

    const int t     = threadIdx.x;
    const int chunk = blockIdx.x;
    const int h     = blockIdx.y;

    // compute-phase tile ownership: 4x4 outer-product per thread
    const int tv = t & 15;   // v-group: v in [tv*4, tv*4+4)
    const int tk = t >> 4;   // k-group: k in [tk*4, tk*4+4)

    // staging-phase ownership: thread covers rows {srow, srow+16}, 4 cols at sc4
    const int srow = t >> 4;         // 0..15
    const int sc4  = (t & 15) * 4;   // 0,4,...,60

    float acc[4][4] = {{0.f}};

    const int base_row = chunk * RPC;

    float4 kA, kB, vA, vB;

    // ---- prologue: stage tile 0 ----
    {
        int rA = base_row + srow;
        int rB = rA + 16;
        kA = *(const float4*)(keys   + (rA * HH + h) * DK + sc4);
        kB = *(const float4*)(keys   + (rB * HH + h) * DK + sc4);
        vA = *(const float4*)(values + (rA * HH + h) * DV + sc4);
        vB = *(const float4*)(values + (rB * HH + h) * DV + sc4);
        float wA = rho[rA], wB = rho[rB];
        kA.x *= wA; kA.y *= wA; kA.z *= wA; kA.w *= wA;
        kB.x *= wB; kB.y *= wB; kB.z *= wB; kB.w *= wB;
        *(float4*)&sK[0][srow * DK + sc4]        = kA;
        *(float4*)&sK[0][(srow + 16) * DK + sc4] = kB;
        *(float4*)&sV[0][srow * DV + sc4]        = vA;
        *(float4*)&sV[0][(srow + 16) * DV + sc4] = vB;
    }
    __syncthreads();

    for (int tile = 0; tile < NT; ++tile) {
        const int cur  = tile & 1;
        const int nxt  = cur ^ 1;
        const bool more = (tile + 1) < NT;

        // issue next tile's global loads early (latency overlaps compute)
        if (more) {
            int rA = base_row + (tile + 1) * TS + srow;
            int rB = rA + 16;
            kA = *(const float4*)(keys   + (rA * HH + h) * DK + sc4);
            kB = *(const float4*)(keys   + (rB * HH + h) * DK + sc4);
            vA = *(const float4*)(values + (rA * HH + h) * DV + sc4);
            vB = *(const float4*)(values + (rB * HH + h) * DV + sc4);
            float wA = rho[rA], wB = rho[rB];
            kA.x *= wA; kA.y *= wA; kA.z *= wA; kA.w *= wA;
            kB.x *= wB; kB.y *= wB; kB.z *= wB; kB.w *= wB;
        }

        const float* kb = sK[cur];
        const float* vb = sV[cur];
        #pragma unroll
        for (int s = 0; s < TS; ++s) {
            float4 kf = *(const float4*)(kb + s * DK + tk * 4);  // 16-lane broadcast
            float4 vf = *(const float4*)(vb + s * DV + tv * 4);  // 2-way (free)
            acc[0][0] = fmaf(kf.x, vf.x, acc[0][0]);
            acc[0][1] = fmaf(kf.x, vf.y, acc[0][1]);
            acc[0][2] = fmaf(kf.x, vf.z, acc[0][2]);
            acc[0][3] = fmaf(kf.x, vf.w, acc[0][3]);
            acc[1][0] = fmaf(kf.y, vf.x, acc[1][0]);
            acc[1][1] = fmaf(kf.y, vf.y, acc[1][1]);
            acc[1][2] = fmaf(kf.y, vf.z, acc[1][2]);
            acc[1][3] = fmaf(kf.y, vf.w, acc[1][3]);
            acc[2][0] = fmaf(kf.z, vf.x, acc[2][0]);
            acc[2][1] = fmaf(kf.z, vf.y, acc[2][1]);
            acc[2][2] = fmaf(kf.z, vf.z, acc[2][2]);
            acc[2][3] = fmaf(kf.z, vf.w, acc[2][3]);
            acc[3][0] = fmaf(kf.w, vf.x, acc[3][0]);
            acc[3][1] = fmaf(kf.w, vf.y, acc[3][1]);
            acc[3][2] = fmaf(kf.w, vf.z, acc[3][2]);
            acc[3][3] = fmaf(kf.w, vf.w, acc[3][3]);
        }
        __syncthreads();   // everyone done reading buf[cur] / prev contents of buf[nxt]
        if (more) {
            *(float4*)&sK[nxt][srow * DK + sc4]        = kA;
            *(float4*)&sK[nxt][(srow + 16) * DK + sc4] = kB;
            *(float4*)&sV[nxt][srow * DV + sc4]        = vA;
            *(float4*)&sV[nxt][(srow + 16) * DV + sc4] = vB;
        }
        __syncthreads();   // staged tile visible before next compute
    }

    // ---- epilogue: block partial -> LDS -> coalesced atomics ----
    float* red = &sK[0][0];   // 2*2048 = 4096 floats, exactly the 64x64 partial
    #pragma unroll
    for (int i = 0; i < 4; ++i)
        #pragma unroll
        for (int j = 0; j < 4; ++j)
            red[(tk * 4 + i) * DV + tv * 4 + j] = acc[i][j];
    __syncthreads();

    float* o = out + h * (DK * DV);
    #pragma unroll
    for (int i = 0; i < 16; ++i)
        atomicAdd(o + i * 256 + t, red[i * 256 + t]);
}

extern "C" void kernel_launch(void* const* d_in, const int* in_sizes, int n_in,
                              void* d_out, int out_size, void* d_ws, size_t ws_size,
                              hipStream_t stream) {
    const float* mem    = (const float*)d_in[0];  // (H, Dk, Dv)
    const float* keys   = (const float*)d_in[1];  // (B, S, H, Dk)
    const float* values = (const float*)d_in[2];  // (B, S, H, Dv)
    const float* rho    = (const float*)d_in[3];  // (B, S)
    float* out = (float*)d_out;                   // (H, Dk, Dv)

    init_out<<<dim3((HH * DK * DV) / 256), dim3(256), 0, stream>>>(mem, out);

    dim3 grid(NCHUNK, HH);
    accum<<<grid, dim3(256), 0, stream>>>(keys, values, rho, out);
}